// Round 9
// baseline (593.908 us; speedup 1.0000x reference)
//
#include <hip/hip_runtime.h>
#include <hip/hip_cooperative_groups.h>

namespace cg = cooperative_groups;

#define NN 200000
#define NE 600000
#define NG 1024
#define HH 512

typedef short short8 __attribute__((ext_vector_type(8)));
typedef float f32x4 __attribute__((ext_vector_type(4)));
typedef unsigned short ushort_t;

__device__ __forceinline__ unsigned short f2bf(float f){
  unsigned u = __float_as_uint(f);
  u += 0x7fffu + ((u >> 16) & 1u);
  return (unsigned short)(u >> 16);
}
__device__ __forceinline__ float bf2f(unsigned short h){
  return __uint_as_float(((unsigned)h) << 16);
}

// gelu(x) = x * sigmoid(1.5957691216*x + 0.07135481627*x^3)  (tanh-form GELU)
__device__ __forceinline__ float gelu_f(float x){
  float p = __builtin_fmaf(x*x, -0.10294325f, -2.3022085f);
  float e = __builtin_amdgcn_exp2f(x * p);
  return x * __builtin_amdgcn_rcpf(1.0f + e);
}

// ========== cooperative front-end: prep + hist + scan + scatter + gh-init, ONE dispatch ==========
__global__ __launch_bounds__(256) void kfront(
    const float* __restrict__ nfw1, const float* __restrict__ nfb1,
    const float* __restrict__ nfg1, const float* __restrict__ nfbe1,
    const float* __restrict__ efw1, const float* __restrict__ efb1,
    const float* __restrict__ efg1, const float* __restrict__ efbe1,
    unsigned short* __restrict__ w1nT, unsigned short* __restrict__ w1eT,
    float* __restrict__ b1n, float* __restrict__ b1e,
    const int* __restrict__ bidx, int* __restrict__ nstart,
    const int* __restrict__ eidx, int* __restrict__ eg, int* __restrict__ cnte,
    int* __restrict__ cursor, int* __restrict__ estart, int* __restrict__ perm,
    const float* __restrict__ w2n, const float* __restrict__ w2e,
    const float* __restrict__ ow1, const float* __restrict__ ow2,
    ushort_t* __restrict__ bt1h, ushort_t* __restrict__ bt1l,
    ushort_t* __restrict__ bt2h, ushort_t* __restrict__ bt2l,
    ushort_t* __restrict__ bt3h, ushort_t* __restrict__ bt3l,
    const float* __restrict__ gf, const float* __restrict__ b2n, const float* __restrict__ b2e,
    float* __restrict__ gh){
  __shared__ int h[NG];
  __shared__ int aux[NG];
  cg::grid_group grid = cg::this_grid();
  const float rs = 0.99999500003750f;   // 1/sqrt(1+1e-5)
  const int b = blockIdx.x, t = threadIdx.x;
  const int gtid = b*256 + t;           // 0..65535

  // ---- phase A ----
  if (gtid < NG) cnte[gtid] = 0;
  // first-layer weights/biases (50176 items, single pass)
  if (gtid < 512*64){
    int c = gtid >> 6, k = gtid & 63;
    float w = (k < 41) ? nfw1[k*HH + c] * nfg1[c] * rs : 0.0f;
    w1nT[gtid] = f2bf(w);
  } else if (gtid < 512*96){
    int u = gtid - 512*64; int c = u >> 5, k = u & 31;
    float w = (k < 16) ? efw1[k*HH + c] * efg1[c] * rs : 0.0f;
    w1eT[u] = f2bf(w);
  } else if (gtid < 512*96 + 512){
    int c = gtid - 512*96;
    b1n[c] = nfb1[c]*nfg1[c]*rs + nfbe1[c];
  } else if (gtid < 512*96 + 1024){
    int c = gtid - (512*96 + 512);
    b1e[c] = efb1[c]*efg1[c]*rs + efbe1[c];
  }
  // finish-weight transposes (bf16 hi/lo, [col][k])
  for (int u = gtid; u < 512*1024; u += 65536){
    int c = u >> 10, k = u & 1023;
    float w = (k < HH) ? w2n[k*HH + c] : w2e[(k-HH)*HH + c];
    unsigned short hh = f2bf(w);
    bt1h[u] = hh; bt1l[u] = f2bf(w - bf2f(hh));
  }
  for (int u = gtid; u < 512*512; u += 65536){
    int c = u >> 9, k = u & 511;
    float w = ow1[k*HH + c];
    unsigned short hh = f2bf(w);
    bt2h[u] = hh; bt2l[u] = f2bf(w - bf2f(hh));
  }
  for (int u = gtid; u < 512*512; u += 65536){
    int c = u >> 9, k = u & 511;
    float w = ow2[k*HH + c];
    unsigned short hh = f2bf(w);
    bt3h[u] = hh; bt3l[u] = f2bf(w - bf2f(hh));
  }
  // node segment boundaries
  for (int i = gtid; i < NN; i += 65536){
    int g0 = bidx[i];
    int g1 = (i+1 < NN) ? bidx[i+1] : NG;
    for (int g = g0+1; g <= g1; ++g) nstart[g] = i+1;
    if (i == 0) for (int g = 0; g <= g0; ++g) nstart[g] = 0;
  }
  // local edge histogram over this block's contiguous range (kept in LDS for scatter phase)
  for (int u = t; u < NG; u += 256) h[u] = 0;
  __syncthreads();
  const int per = (NE + 255) / 256;
  const int lo = b*per, hi = min(lo + per, NE);
  for (int e = lo + t; e < hi; e += 256){
    int g = bidx[eidx[e]];
    eg[e] = g;
    atomicAdd(&h[g], 1);
  }
  grid.sync();

  // ---- phase B: flush histograms ----
  for (int u = t; u < NG; u += 256){ int c = h[u]; if (c) atomicAdd(&cnte[u], c); }
  grid.sync();

  // ---- phase C: exclusive scan (block 0) ----
  if (b == 0){
    int v0 = cnte[t*4], v1 = cnte[t*4+1], v2 = cnte[t*4+2], v3 = cnte[t*4+3];
    int s4 = v0+v1+v2+v3;
    aux[t] = s4;
    __syncthreads();
    for (int d = 1; d < 256; d <<= 1){
      int x = (t >= d) ? aux[t-d] : 0;
      __syncthreads();
      aux[t] += x;
      __syncthreads();
    }
    int b0 = aux[t] - s4;
    estart[t*4]   = b0;           cursor[t*4]   = b0;
    estart[t*4+1] = b0+v0;        cursor[t*4+1] = b0+v0;
    estart[t*4+2] = b0+v0+v1;     cursor[t*4+2] = b0+v0+v1;
    estart[t*4+3] = b0+v0+v1+v2;  cursor[t*4+3] = b0+v0+v1+v2;
    if (t == 255) estart[NG] = aux[255];
  }
  grid.sync();

  // ---- phase D: scatter (reuse LDS hist) + gh-init ----
  for (int u = t; u < NG; u += 256){
    int c = h[u];
    aux[u] = c ? atomicAdd(&cursor[u], c) : 0;
    h[u] = 0;
  }
  __syncthreads();
  for (int e = lo + t; e < hi; e += 256){
    int g = eg[e];
    int p = aux[g] + atomicAdd(&h[g], 1);
    perm[p] = e;
  }
  for (int i = gtid; i < NG*HH/4; i += 65536){
    int f = i*4;
    int r = f >> 9, c = f & 511;
    float cn = (float)(nstart[r+1] - nstart[r]);
    float ce = (float)cnte[r];
    float4 gv = *(const float4*)&gf[f];
    float4 bn4 = *(const float4*)&b2n[c];
    float4 be4 = *(const float4*)&b2e[c];
    float4 o;
    o.x = gv.x + cn*bn4.x + ce*be4.x;
    o.y = gv.y + cn*bn4.y + ce*be4.y;
    o.z = gv.z + cn*bn4.z + ce*be4.z;
    o.w = gv.w + cn*bn4.w + ce*be4.w;
    *(float4*)&gh[f] = o;
  }
}

// ========== fused first layers (round-6 kmain, measured 170us @ VALUBusy 94%) ==========
__global__ __launch_bounds__(256) void kmain(
    const float* __restrict__ nf, const float* __restrict__ dp, const int* __restrict__ ny,
    const int* __restrict__ nstart, const float* __restrict__ ef, const int* __restrict__ perm,
    const int* __restrict__ estart, const unsigned short* __restrict__ w1nT,
    const unsigned short* __restrict__ w1eT, const float* __restrict__ b1n,
    const float* __restrict__ b1e, float* __restrict__ S){
  const int t = threadIdx.x;
  const int lane = t & 63, w = t >> 6;
  const int q = lane >> 4, m = lane & 15;
  const short8 zz = {0,0,0,0,0,0,0,0};
  if (blockIdx.x < 2048){
    // ---------------- EDGE ----------------
    const int g = blockIdx.x >> 1;
    const int c0 = ((blockIdx.x & 1) << 8) + (w << 6);
    short8 bfr[4]; float bias[4]; float colacc[4] = {0.f,0.f,0.f,0.f};
#pragma unroll
    for (int nt=0; nt<4; ++nt){
      int c = c0 + (nt<<4) + m;
      bfr[nt] = *(const short8*)(w1eT + (c << 5) + (q << 3));
      bias[nt] = b1e[c];
    }
    const int s0 = estart[g], s1 = estart[g+1];
    const int nfull = (s1 - s0) >> 4;
    int rb = s0;
    for (int ch=0; ch<nfull; ++ch, rb += 16){
      int e = perm[rb + m];
      short8 f = zz;
      if (q < 2){
        const float4* ap = (const float4*)(ef + (size_t)e*16 + (q<<3));
        float4 xa = ap[0], xb = ap[1];
        f[0]=(short)f2bf(xa.x); f[1]=(short)f2bf(xa.y); f[2]=(short)f2bf(xa.z); f[3]=(short)f2bf(xa.w);
        f[4]=(short)f2bf(xb.x); f[5]=(short)f2bf(xb.y); f[6]=(short)f2bf(xb.z); f[7]=(short)f2bf(xb.w);
      }
#pragma unroll
      for (int nt=0; nt<4; ++nt){
        f32x4 acc = {bias[nt], bias[nt], bias[nt], bias[nt]};
        acc = __builtin_amdgcn_mfma_f32_16x16x32_bf16(f, bfr[nt], acc, 0, 0, 0);
        colacc[nt] += (gelu_f(acc[0]) + gelu_f(acc[1])) + (gelu_f(acc[2]) + gelu_f(acc[3]));
      }
    }
    if (rb < s1){
      int row = rb + m;
      int e = perm[(row < s1) ? row : s0];
      short8 f = zz;
      if (q < 2){
        const float4* ap = (const float4*)(ef + (size_t)e*16 + (q<<3));
        float4 xa = ap[0], xb = ap[1];
        f[0]=(short)f2bf(xa.x); f[1]=(short)f2bf(xa.y); f[2]=(short)f2bf(xa.z); f[3]=(short)f2bf(xa.w);
        f[4]=(short)f2bf(xb.x); f[5]=(short)f2bf(xb.y); f[6]=(short)f2bf(xb.z); f[7]=(short)f2bf(xb.w);
      }
      const int vr = s1 - rb;   // 1..15 valid rows in this chunk
#pragma unroll
      for (int nt=0; nt<4; ++nt){
        f32x4 acc = {bias[nt], bias[nt], bias[nt], bias[nt]};
        acc = __builtin_amdgcn_mfma_f32_16x16x32_bf16(f, bfr[nt], acc, 0, 0, 0);
        float v0 = (q*4+0 < vr) ? gelu_f(acc[0]) : 0.f;
        float v1 = (q*4+1 < vr) ? gelu_f(acc[1]) : 0.f;
        float v2 = (q*4+2 < vr) ? gelu_f(acc[2]) : 0.f;
        float v3 = (q*4+3 < vr) ? gelu_f(acc[3]) : 0.f;
        colacc[nt] += (v0+v1)+(v2+v3);
      }
    }
#pragma unroll
    for (int nt=0; nt<4; ++nt){
      float s = colacc[nt];
      s += __shfl_xor(s, 16); s += __shfl_xor(s, 32);
      if (lane < 16) S[(size_t)g*1024 + 512 + c0 + (nt<<4) + lane] = s;
    }
  } else {
    // ---------------- NODE ----------------
    const int b2 = blockIdx.x - 2048;
    const int g = b2 >> 2;
    const int c0 = ((b2 & 3) << 7) + (w << 5);
    short8 bf0[2], bf1[2]; float bias[2]; float colacc[2] = {0.f,0.f};
#pragma unroll
    for (int nt=0; nt<2; ++nt){
      int c = c0 + (nt<<4) + m;
      const short8* bp = (const short8*)(w1nT + (c << 6) + (q << 3));
      bf0[nt] = bp[0]; bf1[nt] = bp[4];
      bias[nt] = b1n[c];
    }
    const int s0 = nstart[g], s1 = nstart[g+1];
    const int nfull = (s1 - s0) >> 4;
    int rb = s0;
    for (int ch=0; ch<nfull; ++ch, rb += 16){
      int ar = rb + m;
      const float4* ap = (const float4*)(nf + (size_t)ar*32 + (q<<3));
      float4 xa = ap[0], xb = ap[1];
      short8 f;
      f[0]=(short)f2bf(xa.x); f[1]=(short)f2bf(xa.y); f[2]=(short)f2bf(xa.z); f[3]=(short)f2bf(xa.w);
      f[4]=(short)f2bf(xb.x); f[5]=(short)f2bf(xb.y); f[6]=(short)f2bf(xb.z); f[7]=(short)f2bf(xb.w);
      int cls = ny[ar];
      short dpb = (short)f2bf(dp[ar]);
      short8 h = zz;
      if (q == 0){
#pragma unroll
        for (int j=0;j<8;++j) h[j] = (cls==j) ? dpb : (short)0;
      } else if (q == 1 && cls == 8) h[0] = dpb;
#pragma unroll
      for (int nt=0; nt<2; ++nt){
        f32x4 acc = {bias[nt], bias[nt], bias[nt], bias[nt]};
        acc = __builtin_amdgcn_mfma_f32_16x16x32_bf16(f, bf0[nt], acc, 0, 0, 0);
        acc = __builtin_amdgcn_mfma_f32_16x16x32_bf16(h, bf1[nt], acc, 0, 0, 0);
        colacc[nt] += (gelu_f(acc[0]) + gelu_f(acc[1])) + (gelu_f(acc[2]) + gelu_f(acc[3]));
      }
    }
    if (rb < s1){
      int row = rb + m;
      int ar = (row < s1) ? row : s0;
      const float4* ap = (const float4*)(nf + (size_t)ar*32 + (q<<3));
      float4 xa = ap[0], xb = ap[1];
      short8 f;
      f[0]=(short)f2bf(xa.x); f[1]=(short)f2bf(xa.y); f[2]=(short)f2bf(xa.z); f[3]=(short)f2bf(xa.w);
      f[4]=(short)f2bf(xb.x); f[5]=(short)f2bf(xb.y); f[6]=(short)f2bf(xb.z); f[7]=(short)f2bf(xb.w);
      int cls = ny[ar];
      short dpb = (short)f2bf(dp[ar]);
      short8 h = zz;
      if (q == 0){
#pragma unroll
        for (int j=0;j<8;++j) h[j] = (cls==j) ? dpb : (short)0;
      } else if (q == 1 && cls == 8) h[0] = dpb;
      const int vr = s1 - rb;
#pragma unroll
      for (int nt=0; nt<2; ++nt){
        f32x4 acc = {bias[nt], bias[nt], bias[nt], bias[nt]};
        acc = __builtin_amdgcn_mfma_f32_16x16x32_bf16(f, bf0[nt], acc, 0, 0, 0);
        acc = __builtin_amdgcn_mfma_f32_16x16x32_bf16(h, bf1[nt], acc, 0, 0, 0);
        float v0 = (q*4+0 < vr) ? gelu_f(acc[0]) : 0.f;
        float v1 = (q*4+1 < vr) ? gelu_f(acc[1]) : 0.f;
        float v2 = (q*4+2 < vr) ? gelu_f(acc[2]) : 0.f;
        float v3 = (q*4+3 < vr) ? gelu_f(acc[3]) : 0.f;
        colacc[nt] += (v0+v1)+(v2+v3);
      }
    }
#pragma unroll
    for (int nt=0; nt<2; ++nt){
      float s = colacc[nt];
      s += __shfl_xor(s, 16); s += __shfl_xor(s, 32);
      if (lane < 16) S[(size_t)g*1024 + c0 + (nt<<4) + lane] = s;
    }
  }
}

// ========== LDS-free bf16 split (hi+lo) MFMA GEMM tile (device fn) ==========
__device__ __forceinline__ void gemm_nolds(int cx, int ry,
    const float* __restrict__ A, int lda, int nkc,
    const ushort_t* __restrict__ bth, const ushort_t* __restrict__ btl, int ldb,
    float* __restrict__ out, const float* __restrict__ pre, const float* __restrict__ bias,
    const float* __restrict__ gam, const float* __restrict__ bet){
  const int t = threadIdx.x, lane = t & 63, w = t >> 6;
  const int q = lane >> 4, m = lane & 15;
  const int c0 = cx*32, r0 = ry*64 + w*16;
  f32x4 acc[2] = {{0.f,0.f,0.f,0.f},{0.f,0.f,0.f,0.f}};
  const float* ap = A + (size_t)(r0 + m)*lda + (q<<3);
  const ushort_t* bh0 = bth + (size_t)(c0 + m)*ldb + (q<<3);
  const ushort_t* bl0 = btl + (size_t)(c0 + m)*ldb + (q<<3);
  for (int kc = 0; kc < nkc; ++kc){
    const int ko = kc*32;
    float4 x = *(const float4*)(ap + ko);
    float4 y = *(const float4*)(ap + ko + 4);
    float v[8] = {x.x,x.y,x.z,x.w,y.x,y.y,y.z,y.w};
    short8 ah, al;
#pragma unroll
    for (int j=0;j<8;++j){
      unsigned short hh = f2bf(v[j]);
      ah[j] = (short)hh;
      al[j] = (short)f2bf(v[j] - bf2f(hh));
    }
#pragma unroll
    for (int cf=0; cf<2; ++cf){
      short8 bh = *(const short8*)(bh0 + (size_t)(cf*16)*ldb + ko);
      short8 bl = *(const short8*)(bl0 + (size_t)(cf*16)*ldb + ko);
      acc[cf] = __builtin_amdgcn_mfma_f32_16x16x32_bf16(ah, bh, acc[cf], 0, 0, 0);
      acc[cf] = __builtin_amdgcn_mfma_f32_16x16x32_bf16(ah, bl, acc[cf], 0, 0, 0);
      acc[cf] = __builtin_amdgcn_mfma_f32_16x16x32_bf16(al, bh, acc[cf], 0, 0, 0);
    }
  }
  const float rs = 0.99999500003750f;
#pragma unroll
  for (int cf=0; cf<2; ++cf){
    int c = c0 + cf*16 + m;
    float sc = 0.f, bi = 0.f, be = 0.f;
    if (!pre){ sc = gam[c]*rs; bi = bias[c]; be = bet[c]; }
#pragma unroll
    for (int i=0;i<4;++i){
      int r = ry*64 + w*16 + q*4 + i;
      float vv = acc[cf][i];
      if (pre) vv += pre[(size_t)r*HH + c];
      else vv = gelu_f((vv + bi)*sc + be);
      out[(size_t)r*HH + c] = vv;
    }
  }
}

// ========== cooperative back-end: G1 -> G2 -> G3 -> final, one dispatch, no LDS ==========
__global__ __launch_bounds__(256) void kback(
    const float* __restrict__ S,
    const ushort_t* __restrict__ bt1h, const ushort_t* __restrict__ bt1l, float* __restrict__ gh,
    const ushort_t* __restrict__ bt2h, const ushort_t* __restrict__ bt2l,
    const float* __restrict__ ob1, const float* __restrict__ og1, const float* __restrict__ obe1,
    float* __restrict__ xg2,
    const ushort_t* __restrict__ bt3h, const ushort_t* __restrict__ bt3l,
    const float* __restrict__ ob2, const float* __restrict__ og2, const float* __restrict__ obe2,
    float* __restrict__ x2f,
    const float* __restrict__ ow3, const float* __restrict__ ob3, float* __restrict__ out){
  cg::grid_group grid = cg::this_grid();
  const int cx = blockIdx.x & 15, ry = blockIdx.x >> 4;
  // G1: gh = S @ [w2n;w2e] + gh_pre   (K=1024, in-place)
  gemm_nolds(cx, ry, S, 1024, 32, bt1h, bt1l, 1024, gh, gh, nullptr, nullptr, nullptr);
  grid.sync();
  // G2: xg2 = gelu(bn(gh @ ow1 + ob1))
  gemm_nolds(cx, ry, gh, 512, 16, bt2h, bt2l, 512, xg2, nullptr, ob1, og1, obe1);
  grid.sync();
  // G3: x2f = gelu(bn(xg2 @ ow2 + ob2))
  gemm_nolds(cx, ry, xg2, 512, 16, bt3h, bt3l, 512, x2f, nullptr, ob2, og2, obe2);
  grid.sync();
  // final: out = x2f @ ow3 + ob3   (4 rows/block, 1 row/wave)
  const int lane = threadIdx.x & 63, wv = threadIdx.x >> 6;
  const int r = blockIdx.x*4 + wv;
  float a0 = 0.f, a1 = 0.f;
#pragma unroll
  for (int tt=0; tt<8; ++tt){
    int k = lane + tt*64;
    float x = x2f[(size_t)r*HH + k];
    a0 = __builtin_fmaf(x, ow3[2*k], a0);
    a1 = __builtin_fmaf(x, ow3[2*k+1], a1);
  }
#pragma unroll
  for (int d=1; d<64; d<<=1){ a0 += __shfl_xor(a0, d); a1 += __shfl_xor(a1, d); }
  if (lane == 0){ out[r*2] = a0 + ob3[0]; out[r*2+1] = a1 + ob3[1]; }
}

extern "C" void kernel_launch(void* const* d_in, const int* in_sizes, int n_in,
                              void* d_out, int out_size, void* d_ws, size_t ws_size,
                              hipStream_t stream) {
  const float* nf    = (const float*)d_in[0];
  const float* ef    = (const float*)d_in[1];
  const float* gf    = (const float*)d_in[2];
  const float* dp    = (const float*)d_in[3];
  const int*   ny    = (const int*)d_in[4];
  const int*   bidx  = (const int*)d_in[5];
  const int*   eidx  = (const int*)d_in[6];
  const float* nfw1  = (const float*)d_in[7];
  const float* nfb1  = (const float*)d_in[8];
  const float* nfg1  = (const float*)d_in[9];
  const float* nfbe1 = (const float*)d_in[10];
  const float* w2n   = (const float*)d_in[11];
  const float* b2n   = (const float*)d_in[12];
  const float* efw1  = (const float*)d_in[13];
  const float* efb1  = (const float*)d_in[14];
  const float* efg1  = (const float*)d_in[15];
  const float* efbe1 = (const float*)d_in[16];
  const float* w2e   = (const float*)d_in[17];
  const float* b2e   = (const float*)d_in[18];
  const float* ow1   = (const float*)d_in[19];
  const float* ob1   = (const float*)d_in[20];
  const float* og1   = (const float*)d_in[21];
  const float* obe1  = (const float*)d_in[22];
  const float* ow2   = (const float*)d_in[23];
  const float* ob2   = (const float*)d_in[24];
  const float* og2   = (const float*)d_in[25];
  const float* obe2  = (const float*)d_in[26];
  const float* ow3   = (const float*)d_in[27];
  const float* ob3   = (const float*)d_in[28];

  float* S    = (float*)d_ws;                 // 1024 x 1024 (node cols 0-511, edge cols 512-1023)
  int* cnte   = (int*)(S + NG*1024);          // 1024
  int* cursor = cnte + NG;                    // 1024
  int* nstart = cursor + NG;                  // 1025
  int* estart = nstart + NG + 1;              // 1025
  int* eg     = estart + NG + 1;              // NE
  int* perm   = eg + NE;                      // NE
  unsigned short* w1nT = (unsigned short*)(perm + NE);  // 512*64
  unsigned short* w1eT = w1nT + HH*64;                  // 512*32
  float* b1n  = (float*)(w1eT + HH*32);       // 512
  float* b1e  = b1n + HH;                     // 512
  ushort_t* bt1h = (ushort_t*)(b1e + HH);     // 512*1024
  ushort_t* bt1l = bt1h + HH*1024;            // 512*1024
  ushort_t* bt2h = bt1l + HH*1024;            // 512*512
  ushort_t* bt2l = bt2h + HH*HH;              // 512*512
  ushort_t* bt3h = bt2l + HH*HH;              // 512*512
  ushort_t* bt3l = bt3h + HH*HH;              // 512*512
  float* gh   = (float*)(bt3l + HH*HH);       // 1024*512
  float* xg2  = gh + NG*HH;                   // 1024*512
  float* x2f  = xg2 + NG*HH;                  // 1024*512
  float* outf = (float*)d_out;

  void* fargs[] = { (void*)&nfw1, (void*)&nfb1, (void*)&nfg1, (void*)&nfbe1,
                    (void*)&efw1, (void*)&efb1, (void*)&efg1, (void*)&efbe1,
                    (void*)&w1nT, (void*)&w1eT, (void*)&b1n, (void*)&b1e,
                    (void*)&bidx, (void*)&nstart, (void*)&eidx, (void*)&eg, (void*)&cnte,
                    (void*)&cursor, (void*)&estart, (void*)&perm,
                    (void*)&w2n, (void*)&w2e, (void*)&ow1, (void*)&ow2,
                    (void*)&bt1h, (void*)&bt1l, (void*)&bt2h, (void*)&bt2l,
                    (void*)&bt3h, (void*)&bt3l,
                    (void*)&gf, (void*)&b2n, (void*)&b2e, (void*)&gh };
  hipLaunchCooperativeKernel((void*)kfront, dim3(256), dim3(256), fargs, 0, stream);

  kmain<<<6144, 256, 0, stream>>>(nf, dp, ny, nstart, ef, perm, estart,
                                  w1nT, w1eT, b1n, b1e, S);

  void* bargs[] = { (void*)&S, (void*)&bt1h, (void*)&bt1l, (void*)&gh,
                    (void*)&bt2h, (void*)&bt2l, (void*)&ob1, (void*)&og1, (void*)&obe1,
                    (void*)&xg2,
                    (void*)&bt3h, (void*)&bt3l, (void*)&ob2, (void*)&og2, (void*)&obe2,
                    (void*)&x2f,
                    (void*)&ow3, (void*)&ob3, (void*)&outf };
  hipLaunchCooperativeKernel((void*)kback, dim3(256), dim3(256), bargs, 0, stream);
}

// Round 10
// 375.032 us; speedup vs baseline: 1.5836x; 1.5836x over previous
//
#include <hip/hip_runtime.h>

#define NN 200000
#define NE 600000
#define NG 1024
#define HH 512

typedef short short8 __attribute__((ext_vector_type(8)));
typedef float f32x4 __attribute__((ext_vector_type(4)));

__device__ __forceinline__ unsigned short f2bf(float f){
  unsigned u = __float_as_uint(f);
  u += 0x7fffu + ((u >> 16) & 1u);
  return (unsigned short)(u >> 16);
}
__device__ __forceinline__ float bf2f(unsigned short h){
  return __uint_as_float(((unsigned)h) << 16);
}

// gelu(x) = x * sigmoid(1.5957691216*x + 0.07135481627*x^3)  (tanh-form GELU)
__device__ __forceinline__ float gelu_f(float x){
  float p = __builtin_fmaf(x*x, -0.10294325f, -2.3022085f);
  float e = __builtin_amdgcn_exp2f(x * p);
  return x * __builtin_amdgcn_rcpf(1.0f + e);
}

// ========== merged: kprep(196) + kbound(782) + khist_edge(256) ==========
__global__ __launch_bounds__(256) void kpre(
    const float* __restrict__ nfw1, const float* __restrict__ nfb1,
    const float* __restrict__ nfg1, const float* __restrict__ nfbe1,
    const float* __restrict__ efw1, const float* __restrict__ efb1,
    const float* __restrict__ efg1, const float* __restrict__ efbe1,
    unsigned short* __restrict__ w1nT, unsigned short* __restrict__ w1eT,
    float* __restrict__ b1n, float* __restrict__ b1e,
    const int* __restrict__ bidx, int* __restrict__ nstart,
    const int* __restrict__ eidx, int* __restrict__ eg, int* __restrict__ cnte){
  __shared__ int h[NG];
  const float rs = 0.99999500003750f;   // 1/sqrt(1+1e-5)
  int b = blockIdx.x, t = threadIdx.x;
  if (b < 196){
    int tid = b*256 + t;
    if (tid < 512*64){
      int c = tid >> 6, k = tid & 63;
      float w = (k < 41) ? nfw1[k*HH + c] * nfg1[c] * rs : 0.0f;
      w1nT[tid] = f2bf(w);
    } else if (tid < 512*96){
      int u = tid - 512*64; int c = u >> 5, k = u & 31;
      float w = (k < 16) ? efw1[k*HH + c] * efg1[c] * rs : 0.0f;
      w1eT[u] = f2bf(w);
    } else if (tid < 512*96 + 512){
      int c = tid - 512*96;
      b1n[c] = nfb1[c]*nfg1[c]*rs + nfbe1[c];
    } else if (tid < 512*96 + 1024){
      int c = tid - (512*96 + 512);
      b1e[c] = efb1[c]*efg1[c]*rs + efbe1[c];
    }
  } else if (b < 978){
    int i = (b-196)*256 + t;
    if (i < NN){
      int g0 = bidx[i];
      int g1 = (i+1 < NN) ? bidx[i+1] : NG;
      for (int g = g0+1; g <= g1; ++g) nstart[g] = i+1;
      if (i == 0) for (int g = 0; g <= g0; ++g) nstart[g] = 0;
    }
  } else {
    int hb = b - 978;                     // 0..255
    for (int u = t; u < NG; u += 256) h[u] = 0;
    __syncthreads();
    for (int e = hb*256 + t; e < NE; e += 256*256){
      int g = bidx[eidx[e]];
      eg[e] = g;
      atomicAdd(&h[g], 1);
    }
    __syncthreads();
    for (int u = t; u < NG; u += 256){ int c = h[u]; if (c) atomicAdd(&cnte[u], c); }
  }
}

// ========== merged: kscan (block 0, also emits estart) + gh-init (blocks 1..128) ==========
__global__ __launch_bounds__(1024) void kscan_init(const int* __restrict__ cnte, int* __restrict__ cursor,
    int* __restrict__ estart,
    const float* __restrict__ gf, const int* __restrict__ nstart,
    const float* __restrict__ b2n, const float* __restrict__ b2e,
    float* __restrict__ gh){
  if (blockIdx.x == 0){
    __shared__ int s[NG];
    int t = threadIdx.x;
    int v = cnte[t]; s[t] = v; __syncthreads();
    for (int d = 1; d < NG; d <<= 1){
      int x = (t >= d) ? s[t-d] : 0;
      __syncthreads();
      s[t] += x;
      __syncthreads();
    }
    cursor[t] = s[t] - v;
    estart[t] = s[t] - v;
    if (t == NG-1) estart[NG] = s[t];   // == NE
  } else {
    int i = (blockIdx.x - 1)*1024 + threadIdx.x;   // float4 index over 1024*512/4
    int f = i*4;
    int r = f >> 9, c = f & 511;
    float cn = (float)(nstart[r+1] - nstart[r]);
    float ce = (float)cnte[r];
    float4 gv = *(const float4*)&gf[f];
    float4 bn4 = *(const float4*)&b2n[c];
    float4 be4 = *(const float4*)&b2e[c];
    float4 o;
    o.x = gv.x + cn*bn4.x + ce*be4.x;
    o.y = gv.y + cn*bn4.y + ce*be4.y;
    o.z = gv.z + cn*bn4.z + ce*be4.z;
    o.w = gv.w + cn*bn4.w + ce*be4.w;
    *(float4*)&gh[f] = o;
  }
}

// ========== counting-sort scatter (perm only) ==========
__global__ __launch_bounds__(1024) void kscatter(const int* __restrict__ eg, int* __restrict__ cursor,
                                                 int* __restrict__ perm){
  __shared__ int h[NG], base[NG];
  const int per = (NE + gridDim.x - 1) / gridDim.x;
  const int lo = blockIdx.x * per, hi = min(lo + per, NE);
  for (int t = threadIdx.x; t < NG; t += 1024) h[t] = 0;
  __syncthreads();
  for (int e = lo + threadIdx.x; e < hi; e += 1024) atomicAdd(&h[eg[e]], 1);
  __syncthreads();
  for (int t = threadIdx.x; t < NG; t += 1024){
    int c = h[t];
    base[t] = c ? atomicAdd(&cursor[t], c) : 0;
    h[t] = 0;
  }
  __syncthreads();
  for (int e = lo + threadIdx.x; e < hi; e += 1024){
    int g = eg[e];
    int p = base[g] + atomicAdd(&h[g], 1);
    perm[p] = e;
  }
}

// ========== fused first layers (round-6 kmain, measured 170us @ VALUBusy 94%) ==========
__global__ __launch_bounds__(256) void kmain(
    const float* __restrict__ nf, const float* __restrict__ dp, const int* __restrict__ ny,
    const int* __restrict__ nstart, const float* __restrict__ ef, const int* __restrict__ perm,
    const int* __restrict__ estart, const unsigned short* __restrict__ w1nT,
    const unsigned short* __restrict__ w1eT, const float* __restrict__ b1n,
    const float* __restrict__ b1e, float* __restrict__ S){
  const int t = threadIdx.x;
  const int lane = t & 63, w = t >> 6;
  const int q = lane >> 4, m = lane & 15;
  const short8 zz = {0,0,0,0,0,0,0,0};
  if (blockIdx.x < 2048){
    // ---------------- EDGE ----------------
    const int g = blockIdx.x >> 1;
    const int c0 = ((blockIdx.x & 1) << 8) + (w << 6);
    short8 bfr[4]; float bias[4]; float colacc[4] = {0.f,0.f,0.f,0.f};
#pragma unroll
    for (int nt=0; nt<4; ++nt){
      int c = c0 + (nt<<4) + m;
      bfr[nt] = *(const short8*)(w1eT + (c << 5) + (q << 3));
      bias[nt] = b1e[c];
    }
    const int s0 = estart[g], s1 = estart[g+1];
    const int nfull = (s1 - s0) >> 4;
    int rb = s0;
    for (int ch=0; ch<nfull; ++ch, rb += 16){
      int e = perm[rb + m];
      short8 f = zz;
      if (q < 2){
        const float4* ap = (const float4*)(ef + (size_t)e*16 + (q<<3));
        float4 xa = ap[0], xb = ap[1];
        f[0]=(short)f2bf(xa.x); f[1]=(short)f2bf(xa.y); f[2]=(short)f2bf(xa.z); f[3]=(short)f2bf(xa.w);
        f[4]=(short)f2bf(xb.x); f[5]=(short)f2bf(xb.y); f[6]=(short)f2bf(xb.z); f[7]=(short)f2bf(xb.w);
      }
#pragma unroll
      for (int nt=0; nt<4; ++nt){
        f32x4 acc = {bias[nt], bias[nt], bias[nt], bias[nt]};
        acc = __builtin_amdgcn_mfma_f32_16x16x32_bf16(f, bfr[nt], acc, 0, 0, 0);
        colacc[nt] += (gelu_f(acc[0]) + gelu_f(acc[1])) + (gelu_f(acc[2]) + gelu_f(acc[3]));
      }
    }
    if (rb < s1){
      int row = rb + m;
      int e = perm[(row < s1) ? row : s0];
      short8 f = zz;
      if (q < 2){
        const float4* ap = (const float4*)(ef + (size_t)e*16 + (q<<3));
        float4 xa = ap[0], xb = ap[1];
        f[0]=(short)f2bf(xa.x); f[1]=(short)f2bf(xa.y); f[2]=(short)f2bf(xa.z); f[3]=(short)f2bf(xa.w);
        f[4]=(short)f2bf(xb.x); f[5]=(short)f2bf(xb.y); f[6]=(short)f2bf(xb.z); f[7]=(short)f2bf(xb.w);
      }
      const int vr = s1 - rb;   // 1..15 valid rows in this chunk
#pragma unroll
      for (int nt=0; nt<4; ++nt){
        f32x4 acc = {bias[nt], bias[nt], bias[nt], bias[nt]};
        acc = __builtin_amdgcn_mfma_f32_16x16x32_bf16(f, bfr[nt], acc, 0, 0, 0);
        float v0 = (q*4+0 < vr) ? gelu_f(acc[0]) : 0.f;
        float v1 = (q*4+1 < vr) ? gelu_f(acc[1]) : 0.f;
        float v2 = (q*4+2 < vr) ? gelu_f(acc[2]) : 0.f;
        float v3 = (q*4+3 < vr) ? gelu_f(acc[3]) : 0.f;
        colacc[nt] += (v0+v1)+(v2+v3);
      }
    }
#pragma unroll
    for (int nt=0; nt<4; ++nt){
      float s = colacc[nt];
      s += __shfl_xor(s, 16); s += __shfl_xor(s, 32);
      if (lane < 16) S[(size_t)g*1024 + 512 + c0 + (nt<<4) + lane] = s;
    }
  } else {
    // ---------------- NODE ----------------
    const int b2 = blockIdx.x - 2048;
    const int g = b2 >> 2;
    const int c0 = ((b2 & 3) << 7) + (w << 5);
    short8 bf0[2], bf1[2]; float bias[2]; float colacc[2] = {0.f,0.f};
#pragma unroll
    for (int nt=0; nt<2; ++nt){
      int c = c0 + (nt<<4) + m;
      const short8* bp = (const short8*)(w1nT + (c << 6) + (q << 3));
      bf0[nt] = bp[0]; bf1[nt] = bp[4];
      bias[nt] = b1n[c];
    }
    const int s0 = nstart[g], s1 = nstart[g+1];
    const int nfull = (s1 - s0) >> 4;
    int rb = s0;
    for (int ch=0; ch<nfull; ++ch, rb += 16){
      int ar = rb + m;
      const float4* ap = (const float4*)(nf + (size_t)ar*32 + (q<<3));
      float4 xa = ap[0], xb = ap[1];
      short8 f;
      f[0]=(short)f2bf(xa.x); f[1]=(short)f2bf(xa.y); f[2]=(short)f2bf(xa.z); f[3]=(short)f2bf(xa.w);
      f[4]=(short)f2bf(xb.x); f[5]=(short)f2bf(xb.y); f[6]=(short)f2bf(xb.z); f[7]=(short)f2bf(xb.w);
      int cls = ny[ar];
      short dpb = (short)f2bf(dp[ar]);
      short8 h = zz;
      if (q == 0){
#pragma unroll
        for (int j=0;j<8;++j) h[j] = (cls==j) ? dpb : (short)0;
      } else if (q == 1 && cls == 8) h[0] = dpb;
#pragma unroll
      for (int nt=0; nt<2; ++nt){
        f32x4 acc = {bias[nt], bias[nt], bias[nt], bias[nt]};
        acc = __builtin_amdgcn_mfma_f32_16x16x32_bf16(f, bf0[nt], acc, 0, 0, 0);
        acc = __builtin_amdgcn_mfma_f32_16x16x32_bf16(h, bf1[nt], acc, 0, 0, 0);
        colacc[nt] += (gelu_f(acc[0]) + gelu_f(acc[1])) + (gelu_f(acc[2]) + gelu_f(acc[3]));
      }
    }
    if (rb < s1){
      int row = rb + m;
      int ar = (row < s1) ? row : s0;
      const float4* ap = (const float4*)(nf + (size_t)ar*32 + (q<<3));
      float4 xa = ap[0], xb = ap[1];
      short8 f;
      f[0]=(short)f2bf(xa.x); f[1]=(short)f2bf(xa.y); f[2]=(short)f2bf(xa.z); f[3]=(short)f2bf(xa.w);
      f[4]=(short)f2bf(xb.x); f[5]=(short)f2bf(xb.y); f[6]=(short)f2bf(xb.z); f[7]=(short)f2bf(xb.w);
      int cls = ny[ar];
      short dpb = (short)f2bf(dp[ar]);
      short8 h = zz;
      if (q == 0){
#pragma unroll
        for (int j=0;j<8;++j) h[j] = (cls==j) ? dpb : (short)0;
      } else if (q == 1 && cls == 8) h[0] = dpb;
      const int vr = s1 - rb;
#pragma unroll
      for (int nt=0; nt<2; ++nt){
        f32x4 acc = {bias[nt], bias[nt], bias[nt], bias[nt]};
        acc = __builtin_amdgcn_mfma_f32_16x16x32_bf16(f, bf0[nt], acc, 0, 0, 0);
        acc = __builtin_amdgcn_mfma_f32_16x16x32_bf16(h, bf1[nt], acc, 0, 0, 0);
        float v0 = (q*4+0 < vr) ? gelu_f(acc[0]) : 0.f;
        float v1 = (q*4+1 < vr) ? gelu_f(acc[1]) : 0.f;
        float v2 = (q*4+2 < vr) ? gelu_f(acc[2]) : 0.f;
        float v3 = (q*4+3 < vr) ? gelu_f(acc[3]) : 0.f;
        colacc[nt] += (v0+v1)+(v2+v3);
      }
    }
#pragma unroll
    for (int nt=0; nt<2; ++nt){
      float s = colacc[nt];
      s += __shfl_xor(s, 16); s += __shfl_xor(s, 32);
      if (lane < 16) S[(size_t)g*1024 + c0 + (nt<<4) + lane] = s;
    }
  }
}

// ========== LDS-free bf16 split (hi+lo) MFMA GEMM, B loaded directly from fp32 weights ==========
// grid (16 col-tiles x 16 row-tiles); block = 4 waves; wave = 16 rows x 32 cols (2 col-frags).
// A fp32 [rows][lda]: float4x2 per lane + in-reg hi/lo split.
// B fp32 row-major [K][512] (B0 for k<512, B1 beyond): per-lane 8 scalar loads (quad reads 64B
// contiguous), in-reg hi/lo split. No LDS, no barriers, no weight pre-processing.
__global__ __launch_bounds__(256) void kgemm3(const float* __restrict__ A, int lda, int nkc,
    const float* __restrict__ B0, const float* __restrict__ B1,
    float* __restrict__ out, const float* __restrict__ pre, const float* __restrict__ bias,
    const float* __restrict__ gam, const float* __restrict__ bet){
  const int t = threadIdx.x, lane = t & 63, w = t >> 6;
  const int q = lane >> 4, m = lane & 15;
  const int c0 = blockIdx.x*32, r0 = blockIdx.y*64 + w*16;
  f32x4 acc[2] = {{0.f,0.f,0.f,0.f},{0.f,0.f,0.f,0.f}};
  const float* ap = A + (size_t)(r0 + m)*lda + (q<<3);
  for (int kc = 0; kc < nkc; ++kc){
    const int ko = kc*32;
    float4 x = *(const float4*)(ap + ko);
    float4 y = *(const float4*)(ap + ko + 4);
    float v[8] = {x.x,x.y,x.z,x.w,y.x,y.y,y.z,y.w};
    short8 ah, al;
#pragma unroll
    for (int j=0;j<8;++j){
      unsigned short hh = f2bf(v[j]);
      ah[j] = (short)hh;
      al[j] = (short)f2bf(v[j] - bf2f(hh));
    }
    const float* Bp = (kc < 16) ? B0 : B1;
    const float* bp = Bp + (size_t)((kc & 15)*32 + (q<<3))*HH + c0 + m;
#pragma unroll
    for (int cf=0; cf<2; ++cf){
      float bv[8];
#pragma unroll
      for (int j=0;j<8;++j) bv[j] = bp[(size_t)j*HH + cf*16];
      short8 bh, bl;
#pragma unroll
      for (int j=0;j<8;++j){
        unsigned short hh = f2bf(bv[j]);
        bh[j] = (short)hh;
        bl[j] = (short)f2bf(bv[j] - bf2f(hh));
      }
      acc[cf] = __builtin_amdgcn_mfma_f32_16x16x32_bf16(ah, bh, acc[cf], 0, 0, 0);
      acc[cf] = __builtin_amdgcn_mfma_f32_16x16x32_bf16(ah, bl, acc[cf], 0, 0, 0);
      acc[cf] = __builtin_amdgcn_mfma_f32_16x16x32_bf16(al, bh, acc[cf], 0, 0, 0);
    }
  }
  const float rs = 0.99999500003750f;
#pragma unroll
  for (int cf=0; cf<2; ++cf){
    int c = c0 + cf*16 + m;
    float sc = 0.f, bi = 0.f, be = 0.f;
    if (!pre){ sc = gam[c]*rs; bi = bias[c]; be = bet[c]; }
#pragma unroll
    for (int i=0;i<4;++i){
      int r = blockIdx.y*64 + w*16 + q*4 + i;
      float vv = acc[cf][i];
      if (pre) vv += pre[(size_t)r*HH + c];
      else vv = gelu_f((vv + bi)*sc + be);
      out[(size_t)r*HH + c] = vv;
    }
  }
}

// ========== final 512 -> 2 linear ==========
__global__ __launch_bounds__(256) void kfinal(const float* __restrict__ x2, const float* __restrict__ w3,
    const float* __restrict__ b3, float* __restrict__ out){
  const int lane = threadIdx.x & 63, wv = threadIdx.x >> 6;
  const int r = blockIdx.x*4 + wv;
  float a0 = 0.f, a1 = 0.f;
#pragma unroll
  for (int tt=0; tt<8; ++tt){
    int k = lane + tt*64;
    float x = x2[(size_t)r*HH + k];
    a0 = __builtin_fmaf(x, w3[2*k], a0);
    a1 = __builtin_fmaf(x, w3[2*k+1], a1);
  }
#pragma unroll
  for (int d=1; d<64; d<<=1){ a0 += __shfl_xor(a0, d); a1 += __shfl_xor(a1, d); }
  if (lane == 0){ out[r*2] = a0 + b3[0]; out[r*2+1] = a1 + b3[1]; }
}

extern "C" void kernel_launch(void* const* d_in, const int* in_sizes, int n_in,
                              void* d_out, int out_size, void* d_ws, size_t ws_size,
                              hipStream_t stream) {
  const float* nf    = (const float*)d_in[0];
  const float* ef    = (const float*)d_in[1];
  const float* gf    = (const float*)d_in[2];
  const float* dp    = (const float*)d_in[3];
  const int*   ny    = (const int*)d_in[4];
  const int*   bidx  = (const int*)d_in[5];
  const int*   eidx  = (const int*)d_in[6];
  const float* nfw1  = (const float*)d_in[7];
  const float* nfb1  = (const float*)d_in[8];
  const float* nfg1  = (const float*)d_in[9];
  const float* nfbe1 = (const float*)d_in[10];
  const float* w2n   = (const float*)d_in[11];
  const float* b2n   = (const float*)d_in[12];
  const float* efw1  = (const float*)d_in[13];
  const float* efb1  = (const float*)d_in[14];
  const float* efg1  = (const float*)d_in[15];
  const float* efbe1 = (const float*)d_in[16];
  const float* w2e   = (const float*)d_in[17];
  const float* b2e   = (const float*)d_in[18];
  const float* ow1   = (const float*)d_in[19];
  const float* ob1   = (const float*)d_in[20];
  const float* og1   = (const float*)d_in[21];
  const float* obe1  = (const float*)d_in[22];
  const float* ow2   = (const float*)d_in[23];
  const float* ob2   = (const float*)d_in[24];
  const float* og2   = (const float*)d_in[25];
  const float* obe2  = (const float*)d_in[26];
  const float* ow3   = (const float*)d_in[27];
  const float* ob3   = (const float*)d_in[28];

  float* S    = (float*)d_ws;                 // 1024 x 1024 (node cols 0-511, edge cols 512-1023)
  int* cnte   = (int*)(S + NG*1024);          // 1024
  int* cursor = cnte + NG;                    // 1024
  int* nstart = cursor + NG;                  // 1025
  int* estart = nstart + NG + 1;              // 1025
  int* eg     = estart + NG + 1;              // NE
  int* perm   = eg + NE;                      // NE
  unsigned short* w1nT = (unsigned short*)(perm + NE);  // 512*64
  unsigned short* w1eT = w1nT + HH*64;                  // 512*32
  float* b1n  = (float*)(w1eT + HH*32);       // 512
  float* b1e  = b1n + HH;                     // 512
  float* gh   = b1e + HH;                     // 1024*512
  float* xg2  = gh + NG*HH;                   // 1024*512
  float* x2f  = xg2 + NG*HH;                  // 1024*512

  hipMemsetAsync(cnte, 0, NG*sizeof(int), stream);   // only the histogram needs zeroing

  kpre<<<1234, 256, 0, stream>>>(nfw1, nfb1, nfg1, nfbe1, efw1, efb1, efg1, efbe1,
                                 w1nT, w1eT, b1n, b1e, bidx, nstart, eidx, eg, cnte);
  kscan_init<<<129, 1024, 0, stream>>>(cnte, cursor, estart, gf, nstart, b2n, b2e, gh);
  kscatter<<<128, 1024, 0, stream>>>(eg, cursor, perm);
  kmain<<<6144, 256, 0, stream>>>(nf, dp, ny, nstart, ef, perm, estart,
                                  w1nT, w1eT, b1n, b1e, S);
  // G1: gh = S @ [w2n;w2e] + gh_pre   (K=1024, in-place pre)
  kgemm3<<<dim3(16,16), 256, 0, stream>>>(S, 1024, 32, w2n, w2e, gh, gh,
                                          nullptr, nullptr, nullptr);
  // G2: xg2 = gelu(bn(gh @ ow1 + ob1))
  kgemm3<<<dim3(16,16), 256, 0, stream>>>(gh, 512, 16, ow1, ow1, xg2, nullptr,
                                          ob1, og1, obe1);
  // G3: x2f = gelu(bn(xg2 @ ow2 + ob2))
  kgemm3<<<dim3(16,16), 256, 0, stream>>>(xg2, 512, 16, ow2, ow2, x2f, nullptr,
                                          ob2, og2, obe2);
  kfinal<<<NG/4, 256, 0, stream>>>(x2f, ow3, ob3, (float*)d_out);
}